// Round 1
// baseline (1693.340 us; speedup 1.0000x reference)
//
#include <hip/hip_runtime.h>
#include <hip/hip_bf16.h>

#define Vn   196608
#define NNZn 1769472
#define Bn   4
#define Pn   64
#define Qn   64
#define VPn  (Vn*Pn)

typedef __hip_bfloat16 bf16;

// ---------------- CSR build (counting sort) ----------------

__global__ void k_zero(unsigned* __restrict__ p, int n){
  int i = blockIdx.x*blockDim.x + threadIdx.x;
  if(i<n) p[i]=0u;
}

__global__ void k_hist(const int* __restrict__ rows, unsigned* __restrict__ counts){
  int i = blockIdx.x*blockDim.x + threadIdx.x;   // grid covers NNZ exactly
  atomicAdd(&counts[rows[i]], 1u);
}

__global__ __launch_bounds__(1024) void k_scan_block(const unsigned* __restrict__ counts,
                                                     unsigned* __restrict__ incl,
                                                     unsigned* __restrict__ bsums){
  __shared__ unsigned s[1024];
  const int tid = threadIdx.x;
  const int gid = blockIdx.x*1024 + tid;
  s[tid] = counts[gid];
  __syncthreads();
  for(int off=1; off<1024; off<<=1){
    unsigned v = (tid>=off) ? s[tid-off] : 0u;
    __syncthreads();
    s[tid] += v;
    __syncthreads();
  }
  incl[gid] = s[tid];
  if(tid==1023) bsums[blockIdx.x] = s[1023];
}

__global__ void k_scan_top(unsigned* __restrict__ bs){
  if(blockIdx.x==0 && threadIdx.x==0){
    unsigned acc=0u;
    for(int i=0;i<192;i++){ unsigned t=bs[i]; bs[i]=acc; acc+=t; }
  }
}

__global__ void k_scan_add(const unsigned* __restrict__ counts, unsigned* __restrict__ incl,
                           const unsigned* __restrict__ boffs,
                           unsigned* __restrict__ rstart, unsigned* __restrict__ cursor){
  int i = blockIdx.x*blockDim.x + threadIdx.x;   // grid covers V exactly
  unsigned e = incl[i] + boffs[i>>10];
  incl[i] = e;
  unsigned st = e - counts[i];
  rstart[i] = st;
  cursor[i] = st;
}

__global__ void k_scatter(const float* __restrict__ vals, const int* __restrict__ rows,
                          const int* __restrict__ cols, unsigned* __restrict__ cursor,
                          float* __restrict__ svals, int* __restrict__ scols){
  int i = blockIdx.x*blockDim.x + threadIdx.x;   // grid covers NNZ exactly
  int r = rows[i];
  unsigned pos = atomicAdd(&cursor[r], 1u);
  svals[pos] = vals[i];
  scols[pos] = cols[i];
}

// ---------------- SpMM: one wave per row, lane = p, 4 batches per lane ----------------
// dst layout: [V][B][P] bf16.  Src: template (x is fp32 [B][V][P]; x1 is bf16 [V][B][P]).

template<typename TS, int RS, int BS>
__global__ __launch_bounds__(256) void k_spmm(const TS* __restrict__ src,
                          const float* __restrict__ svals, const int* __restrict__ scols,
                          const unsigned* __restrict__ rstart, const unsigned* __restrict__ rend,
                          bf16* __restrict__ dst){
  const int lane = threadIdx.x & 63;
  const int v = (blockIdx.x<<2) + (threadIdx.x>>6);
  const unsigned s = rstart[v], e = rend[v];
  float a0=0.f, a1=0.f, a2=0.f, a3=0.f;
  for(unsigned j=s; j<e; ++j){
    const float w = svals[j];
    const size_t c = (size_t)scols[j];
    const TS* xp = src + c*(size_t)RS + lane;
    a0 = fmaf(w, (float)xp[0],      a0);
    a1 = fmaf(w, (float)xp[BS],     a1);
    a2 = fmaf(w, (float)xp[2*BS],   a2);
    a3 = fmaf(w, (float)xp[3*BS],   a3);
  }
  bf16* o = dst + (size_t)v*256 + lane;
  o[0]   = __float2bfloat16(a0);
  o[64]  = __float2bfloat16(a1);
  o[128] = __float2bfloat16(a2);
  o[192] = __float2bfloat16(a3);
}

// ---------------- GEMM epilogue ----------------
// out[b,v,q] = bias[q] + sum_p x[b,v,p]*(W0-W2)[p,q] + x1[v,b,p]*W1[p,q] + y[v,b,p]*(2*W2)[p,q]
// where Wk[p][q] = wf[(3p+k)*64+q]  (torch mismatched-flatten semantics).

#define WP 68
__global__ __launch_bounds__(256) void k_gemm(const float* __restrict__ x,
                      const bf16* __restrict__ x1, const bf16* __restrict__ y,
                      const float* __restrict__ wf, const float* __restrict__ bias,
                      float* __restrict__ out){
  __shared__ __align__(16) float sw[3*64*WP];   // 52224 B, transposed [k][q][p], pitch 68
  __shared__ __align__(16) float si[4*768];     // 12288 B: 4 rows x (x | x1 | y) x [b][p]
  const int t = threadIdx.x;
  for(int idx=t; idx<3*4096; idx+=256){
    const int k = idx>>12, r = idx&4095, p = r>>6, q = r&63;
    float w;
    if(k==0)      w = wf[(3*p+0)*64+q] - wf[(3*p+2)*64+q];
    else if(k==1) w = wf[(3*p+1)*64+q];
    else          w = 2.0f*wf[(3*p+2)*64+q];
    sw[(k*64+q)*WP + p] = w;
  }
  const int b = t>>6, q = t&63;
  const float bi = bias[q];
  const size_t v0 = (size_t)blockIdx.x*64;
  for(int g=0; g<16; ++g){
    const size_t vg = v0 + (size_t)g*4;
    __syncthreads();
    for(int idx=t; idx<3072; idx+=256){
      const int r = idx/768, c = idx%768;
      const int arr = c>>8, bp = c&255;
      float val;
      if(arr==0){ const int bb=bp>>6, p=bp&63; val = x[(size_t)bb*VPn + (vg+r)*64 + p]; }
      else if(arr==1){ val = (float)x1[(vg+r)*256 + bp]; }
      else            { val = (float)y [(vg+r)*256 + bp]; }
      si[idx] = val;
    }
    __syncthreads();
    float acc[4];
#pragma unroll
    for(int r=0;r<4;++r) acc[r]=bi;
    for(int p=0;p<64;p+=4){
      const float4 w0 = *(const float4*)&sw[(0*64+q)*WP+p];
      const float4 w1 = *(const float4*)&sw[(1*64+q)*WP+p];
      const float4 w2 = *(const float4*)&sw[(2*64+q)*WP+p];
#pragma unroll
      for(int r=0;r<4;++r){
        const float4 xv = *(const float4*)&si[r*768 +       (b<<6) + p];
        const float4 av = *(const float4*)&si[r*768 + 256 + (b<<6) + p];
        const float4 yv = *(const float4*)&si[r*768 + 512 + (b<<6) + p];
        float s = acc[r];
        s = fmaf(xv.x, w0.x, s); s = fmaf(xv.y, w0.y, s);
        s = fmaf(xv.z, w0.z, s); s = fmaf(xv.w, w0.w, s);
        s = fmaf(av.x, w1.x, s); s = fmaf(av.y, w1.y, s);
        s = fmaf(av.z, w1.z, s); s = fmaf(av.w, w1.w, s);
        s = fmaf(yv.x, w2.x, s); s = fmaf(yv.y, w2.y, s);
        s = fmaf(yv.z, w2.z, s); s = fmaf(yv.w, w2.w, s);
        acc[r] = s;
      }
    }
#pragma unroll
    for(int r=0;r<4;++r)
      out[((size_t)b*Vn + vg + r)*64 + q] = acc[r];
  }
}

// ---------------- launch ----------------

extern "C" void kernel_launch(void* const* d_in, const int* in_sizes, int n_in,
                              void* d_out, int out_size, void* d_ws, size_t ws_size,
                              hipStream_t stream){
  const float* lap_vals = (const float*)d_in[0];
  const float* x        = (const float*)d_in[1];
  const float* weight   = (const float*)d_in[2];
  const float* bias     = (const float*)d_in[3];
  const int*   lap_rows = (const int*)d_in[4];
  const int*   lap_cols = (const int*)d_in[5];
  float* out = (float*)d_out;

  char* w = (char*)d_ws;
  bf16* x1b = (bf16*)w;            w += (size_t)Vn*256*sizeof(bf16);
  bf16* yb  = (bf16*)w;            w += (size_t)Vn*256*sizeof(bf16);
  float* svals = (float*)w;        w += (size_t)NNZn*4;
  int*   scols = (int*)w;          w += (size_t)NNZn*4;
  unsigned* counts = (unsigned*)w; w += (size_t)Vn*4;
  unsigned* cursor = (unsigned*)w; w += (size_t)Vn*4;
  unsigned* rstart = (unsigned*)w; w += (size_t)Vn*4;
  unsigned* rend   = (unsigned*)w; w += (size_t)Vn*4;
  unsigned* bsums  = (unsigned*)w; w += 1024;

  k_zero<<<Vn/256, 256, 0, stream>>>(counts, Vn);
  k_hist<<<NNZn/256, 256, 0, stream>>>(lap_rows, counts);
  k_scan_block<<<192, 1024, 0, stream>>>(counts, rend, bsums);
  k_scan_top<<<1, 64, 0, stream>>>(bsums);
  k_scan_add<<<Vn/256, 256, 0, stream>>>(counts, rend, bsums, rstart, cursor);
  k_scatter<<<NNZn/256, 256, 0, stream>>>(lap_vals, lap_rows, lap_cols, cursor, svals, scols);

  // x1 = L @ x0   (gather from x: [B][V][P], row stride 64, batch stride V*P)
  k_spmm<float, 64, VPn><<<Vn/4, 256, 0, stream>>>(x, svals, scols, rstart, rend, x1b);
  // y = L @ x1    (gather from x1: [V][B][P] bf16, row stride 256, batch stride 64)
  k_spmm<bf16, 256, 64><<<Vn/4, 256, 0, stream>>>(x1b, svals, scols, rstart, rend, yb);

  k_gemm<<<Vn/64, 256, 0, stream>>>(x, x1b, yb, weight, bias, out);
}

// Round 2
// 823.025 us; speedup vs baseline: 2.0575x; 2.0575x over previous
//
#include <hip/hip_runtime.h>
#include <hip/hip_bf16.h>

#define Vn   196608
#define NNZn 1769472
#define Bn   4
#define Pn   64
#define Qn   64
#define VPn  (Vn*Pn)

typedef __hip_bfloat16 bf16;
typedef __attribute__((ext_vector_type(8))) short bf16x8;
typedef __attribute__((ext_vector_type(4))) float f32x4;

__device__ inline short f2bs(float f){
  __hip_bfloat16 h = __float2bfloat16(f);
  return *(short*)&h;
}

// ---------------- CSR build (counting sort) ----------------

__global__ void k_zero(unsigned* __restrict__ p, int n){
  int i = blockIdx.x*blockDim.x + threadIdx.x;
  if(i<n) p[i]=0u;
}

__global__ void k_hist(const int* __restrict__ rows, unsigned* __restrict__ counts){
  int i = blockIdx.x*blockDim.x + threadIdx.x;   // grid covers NNZ exactly
  atomicAdd(&counts[rows[i]], 1u);
}

__global__ __launch_bounds__(1024) void k_scan_block(const unsigned* __restrict__ counts,
                                                     unsigned* __restrict__ incl,
                                                     unsigned* __restrict__ bsums){
  __shared__ unsigned s[1024];
  const int tid = threadIdx.x;
  const int gid = blockIdx.x*1024 + tid;
  s[tid] = counts[gid];
  __syncthreads();
  for(int off=1; off<1024; off<<=1){
    unsigned v = (tid>=off) ? s[tid-off] : 0u;
    __syncthreads();
    s[tid] += v;
    __syncthreads();
  }
  incl[gid] = s[tid];
  if(tid==1023) bsums[blockIdx.x] = s[1023];
}

__global__ void k_scan_top(unsigned* __restrict__ bs){
  if(blockIdx.x==0 && threadIdx.x==0){
    unsigned acc=0u;
    for(int i=0;i<192;i++){ unsigned t=bs[i]; bs[i]=acc; acc+=t; }
  }
}

__global__ void k_scan_add(const unsigned* __restrict__ counts, unsigned* __restrict__ incl,
                           const unsigned* __restrict__ boffs,
                           unsigned* __restrict__ rstart, unsigned* __restrict__ cursor){
  int i = blockIdx.x*blockDim.x + threadIdx.x;   // grid covers V exactly
  unsigned e = incl[i] + boffs[i>>10];
  incl[i] = e;
  unsigned st = e - counts[i];
  rstart[i] = st;
  cursor[i] = st;
}

__global__ void k_scatter(const float* __restrict__ vals, const int* __restrict__ rows,
                          const int* __restrict__ cols, unsigned* __restrict__ cursor,
                          float* __restrict__ svals, int* __restrict__ scols){
  int i = blockIdx.x*blockDim.x + threadIdx.x;   // grid covers NNZ exactly
  int r = rows[i];
  unsigned pos = atomicAdd(&cursor[r], 1u);
  svals[pos] = vals[i];
  scols[pos] = cols[i];
}

// ---------------- SpMM: one wave per row, lane = p, 4 batches per lane ----------------
// dst layout: [V][B][P] bf16.  Src: template (x is fp32 [B][V][P]; x1 is bf16 [V][B][P]).

template<typename TS, int RS, int BS>
__global__ __launch_bounds__(256) void k_spmm(const TS* __restrict__ src,
                          const float* __restrict__ svals, const int* __restrict__ scols,
                          const unsigned* __restrict__ rstart, const unsigned* __restrict__ rend,
                          bf16* __restrict__ dst){
  const int lane = threadIdx.x & 63;
  const int v = (blockIdx.x<<2) + (threadIdx.x>>6);
  const unsigned s = rstart[v], e = rend[v];
  float a0=0.f, a1=0.f, a2=0.f, a3=0.f;
  for(unsigned j=s; j<e; ++j){
    const float w = svals[j];
    const size_t c = (size_t)scols[j];
    const TS* xp = src + c*(size_t)RS + lane;
    a0 = fmaf(w, (float)xp[0],      a0);
    a1 = fmaf(w, (float)xp[BS],     a1);
    a2 = fmaf(w, (float)xp[2*BS],   a2);
    a3 = fmaf(w, (float)xp[3*BS],   a3);
  }
  bf16* o = dst + (size_t)v*256 + lane;
  o[0]   = __float2bfloat16(a0);
  o[64]  = __float2bfloat16(a1);
  o[128] = __float2bfloat16(a2);
  o[192] = __float2bfloat16(a3);
}

// ---------------- combined weights: wcb[q][k3], k3 = part*64 + p ----------------
// part0: W0-W2, part1: W1, part2: 2*W2, where Wk[p][q] = wf[(3p+k)*64+q].

__global__ void k_prepw(const float* __restrict__ wf, short* __restrict__ wcb){
  int idx = blockIdx.x*256 + threadIdx.x;      // 12288 total
  int q = idx/192, rem = idx%192, part = rem>>6, p = rem&63;
  float w;
  if(part==0)      w = wf[(3*p+0)*64+q] - wf[(3*p+2)*64+q];
  else if(part==1) w = wf[(3*p+1)*64+q];
  else             w = 2.0f*wf[(3*p+2)*64+q];
  wcb[idx] = f2bs(w);
}

// ---------------- MFMA GEMM epilogue ----------------
// out[b,v,q] = bias[q] + sum over k3 of A[v-row, k3] * Wc[k3, q]
// A parts: k3 in [0,64): bf16(x[b][v][p]); [64,128): x1[v][b][p]; [128,192): y[v][b][p].
// mfma_f32_16x16x32_bf16 fragments: A row=l&15, k=8*(l>>4)+i (contiguous 8);
// B col=l&15, k=8*(l>>4)+i; C/D col=l&15, row=4*(l>>4)+reg  [m89/m92/m97-verified pattern].

#define WTP 200   // LDS pitch in bf16 elems: bank stride 4 -> uniform, conflict-free

__global__ __launch_bounds__(256) void k_gemm_mfma(const float* __restrict__ x,
                      const short* __restrict__ x1, const short* __restrict__ y,
                      const short* __restrict__ wcb, const float* __restrict__ bias,
                      float* __restrict__ out){
  __shared__ short WT[64*WTP];    // 25600 B, [q][k3] padded
  const int t = threadIdx.x;
  for(int idx=t; idx<1536; idx+=256){
    const int row = idx/24, ch = idx%24;
    *(uint4*)&WT[row*WTP + ch*8] = ((const uint4*)wcb)[row*24 + ch];
  }
  const int w = t>>6;          // wave id = batch b
  const int l = t&63, r = l&15, g = l>>4;
  const size_t v0 = (size_t)blockIdx.x*64;
  f32x4 acc[4][4] = {};
  __syncthreads();

  for(int c=0; c<6; ++c){
    const int part = c>>1, ko = (c&1)*32;       // offset within part
    bf16x8 a[4];
    if(part==0){
      const float* xp = x + (size_t)w*VPn + (v0 + r)*64 + ko + 8*g;
#pragma unroll
      for(int m=0;m<4;++m){
        const float* p2 = xp + (size_t)m*16*64;
        const float4 f0 = *(const float4*)p2;
        const float4 f1 = *(const float4*)(p2+4);
        bf16x8 av;
        av[0]=f2bs(f0.x); av[1]=f2bs(f0.y); av[2]=f2bs(f0.z); av[3]=f2bs(f0.w);
        av[4]=f2bs(f1.x); av[5]=f2bs(f1.y); av[6]=f2bs(f1.z); av[7]=f2bs(f1.w);
        a[m]=av;
      }
    } else {
      const short* sp = (part==1 ? x1 : y) + ((v0 + r)*256 + w*64 + ko + 8*g);
#pragma unroll
      for(int m=0;m<4;++m) a[m] = *(const bf16x8*)(sp + (size_t)m*16*256);
    }
    const int kw = part*64 + ko + 8*g;          // k3 offset into WT row
#pragma unroll
    for(int n=0;n<4;++n){
      const bf16x8 bfr = *(const bf16x8*)&WT[(n*16+r)*WTP + kw];
#pragma unroll
      for(int m=0;m<4;++m)
        acc[m][n] = __builtin_amdgcn_mfma_f32_16x16x32_bf16(a[m], bfr, acc[m][n], 0, 0, 0);
    }
  }

  float* ob = out + (size_t)w*Vn*64 + v0*64;
#pragma unroll
  for(int n=0;n<4;++n){
    const float bq = bias[n*16+r];
#pragma unroll
    for(int m=0;m<4;++m){
#pragma unroll
      for(int reg=0;reg<4;++reg){
        const int row = m*16 + g*4 + reg;
        ob[(size_t)row*64 + n*16 + r] = acc[m][n][reg] + bq;
      }
    }
  }
}

// ---------------- launch ----------------

extern "C" void kernel_launch(void* const* d_in, const int* in_sizes, int n_in,
                              void* d_out, int out_size, void* d_ws, size_t ws_size,
                              hipStream_t stream){
  const float* lap_vals = (const float*)d_in[0];
  const float* x        = (const float*)d_in[1];
  const float* weight   = (const float*)d_in[2];
  const float* bias     = (const float*)d_in[3];
  const int*   lap_rows = (const int*)d_in[4];
  const int*   lap_cols = (const int*)d_in[5];
  float* out = (float*)d_out;

  char* w = (char*)d_ws;
  bf16* x1b = (bf16*)w;            w += (size_t)Vn*256*sizeof(bf16);
  bf16* yb  = (bf16*)w;            w += (size_t)Vn*256*sizeof(bf16);
  float* svals = (float*)w;        w += (size_t)NNZn*4;
  int*   scols = (int*)w;          w += (size_t)NNZn*4;
  unsigned* counts = (unsigned*)w; w += (size_t)Vn*4;
  unsigned* cursor = (unsigned*)w; w += (size_t)Vn*4;
  unsigned* rstart = (unsigned*)w; w += (size_t)Vn*4;
  unsigned* rend   = (unsigned*)w; w += (size_t)Vn*4;
  unsigned* bsums  = (unsigned*)w; w += 1024;
  short* wcb = (short*)w;          w += 12288*sizeof(short);

  k_zero<<<Vn/256, 256, 0, stream>>>(counts, Vn);
  k_hist<<<NNZn/256, 256, 0, stream>>>(lap_rows, counts);
  k_scan_block<<<192, 1024, 0, stream>>>(counts, rend, bsums);
  k_scan_top<<<1, 64, 0, stream>>>(bsums);
  k_scan_add<<<Vn/256, 256, 0, stream>>>(counts, rend, bsums, rstart, cursor);
  k_scatter<<<NNZn/256, 256, 0, stream>>>(lap_vals, lap_rows, lap_cols, cursor, svals, scols);
  k_prepw<<<48, 256, 0, stream>>>(weight, wcb);

  // x1 = L @ x0   (gather from x: [B][V][P], row stride 64, batch stride V*P)
  k_spmm<float, 64, VPn><<<Vn/4, 256, 0, stream>>>(x, svals, scols, rstart, rend, x1b);
  // y = L @ x1    (gather from x1: [V][B][P] bf16, row stride 256, batch stride 64)
  k_spmm<bf16, 256, 64><<<Vn/4, 256, 0, stream>>>(x1b, svals, scols, rstart, rend, yb);

  k_gemm_mfma<<<Vn/64, 256, 0, stream>>>(x, (const short*)x1b, (const short*)yb,
                                         wcb, bias, out);
}

// Round 3
// 780.675 us; speedup vs baseline: 2.1691x; 1.0542x over previous
//
#include <hip/hip_runtime.h>
#include <hip/hip_bf16.h>

#define Vn   196608
#define NNZn 1769472
#define Bn   4
#define Pn   64
#define Qn   64
#define VPn  (Vn*Pn)

typedef __hip_bfloat16 bf16;
typedef __attribute__((ext_vector_type(8))) short bf16x8;
typedef __attribute__((ext_vector_type(4))) float f32x4;

__device__ inline short f2bs(float f){
  __hip_bfloat16 h = __float2bfloat16(f);
  return *(short*)&h;
}
__device__ inline float bs2f(unsigned short s){
  return __uint_as_float(((unsigned)s)<<16);
}

// ---------------- CSR build (counting sort) ----------------

__global__ void k_zero(unsigned* __restrict__ p, int n){
  int i = blockIdx.x*blockDim.x + threadIdx.x;
  if(i<n) p[i]=0u;
}

__global__ void k_hist(const int* __restrict__ rows, unsigned* __restrict__ counts){
  int i = blockIdx.x*blockDim.x + threadIdx.x;   // grid covers NNZ exactly
  atomicAdd(&counts[rows[i]], 1u);
}

__global__ __launch_bounds__(1024) void k_scan_block(const unsigned* __restrict__ counts,
                                                     unsigned* __restrict__ incl,
                                                     unsigned* __restrict__ bsums){
  __shared__ unsigned s[1024];
  const int tid = threadIdx.x;
  const int gid = blockIdx.x*1024 + tid;
  s[tid] = counts[gid];
  __syncthreads();
  for(int off=1; off<1024; off<<=1){
    unsigned v = (tid>=off) ? s[tid-off] : 0u;
    __syncthreads();
    s[tid] += v;
    __syncthreads();
  }
  incl[gid] = s[tid];
  if(tid==1023) bsums[blockIdx.x] = s[1023];
}

__global__ void k_scan_top(unsigned* __restrict__ bs){
  if(blockIdx.x==0 && threadIdx.x==0){
    unsigned acc=0u;
    for(int i=0;i<192;i++){ unsigned t=bs[i]; bs[i]=acc; acc+=t; }
  }
}

__global__ void k_scan_add(const unsigned* __restrict__ counts, unsigned* __restrict__ incl,
                           const unsigned* __restrict__ boffs,
                           unsigned* __restrict__ rstart, unsigned* __restrict__ cursor){
  int i = blockIdx.x*blockDim.x + threadIdx.x;   // grid covers V exactly
  unsigned e = incl[i] + boffs[i>>10];
  incl[i] = e;
  unsigned st = e - counts[i];
  rstart[i] = st;
  cursor[i] = st;
}

__global__ void k_scatter(const float* __restrict__ vals, const int* __restrict__ rows,
                          const int* __restrict__ cols, unsigned* __restrict__ cursor,
                          float* __restrict__ svals, int* __restrict__ scols){
  int i = blockIdx.x*blockDim.x + threadIdx.x;   // grid covers NNZ exactly
  int r = rows[i];
  unsigned pos = atomicAdd(&cursor[r], 1u);
  svals[pos] = vals[i];
  scols[pos] = cols[i];
}

// ---------------- x -> bf16 x0c, stored INSIDE d_out ----------------
// x0c piece h (h=b>>1) of row v lives at shorts offset (h*Vn + v)*128, i.e.
// exactly the out-fp32 bytes of batch h, row v -- each gemm block's x0 reads
// are inside its own out-write region (race-free with an intra-block barrier).

__global__ void k_cvt(const float* __restrict__ x, short* __restrict__ x0c){
  const int i = blockIdx.x*256 + threadIdx.x;    // V*256/4 threads
  const int o = i*4;
  const int v = o>>8, bp = o&255;
  const int h = bp>>7, w7 = bp&127;
  const int b = (h<<1) + (w7>>6), p = w7&63;
  const float4 f = *(const float4*)(x + (size_t)b*VPn + (size_t)v*64 + p);
  ushort4 u;
  u.x = (unsigned short)f2bs(f.x); u.y = (unsigned short)f2bs(f.y);
  u.z = (unsigned short)f2bs(f.z); u.w = (unsigned short)f2bs(f.w);
  *(ushort4*)(x0c + ((size_t)h*Vn + v)*128 + w7) = u;
}

// ---------------- SpMM: one wave per row, lane covers 4 consecutive elems ----
// dst: flat [V][256] bf16. Source addressing: elem e of row c at
// src + c*SROW + (e>>7)*PSTR + (e&127)   (SROW=256,PSTR=128 -> flat).

template<int SROW, size_t PSTR>
__global__ __launch_bounds__(256) void k_spmm(const short* __restrict__ src,
                          const float* __restrict__ svals, const int* __restrict__ scols,
                          const unsigned* __restrict__ rstart, const unsigned* __restrict__ rend,
                          short* __restrict__ dst){
  const int lane = threadIdx.x & 63;
  const int v = (blockIdx.x<<2) + (threadIdx.x>>6);
  const unsigned s = rstart[v], e = rend[v];
  const size_t off = (size_t)(lane>>5)*PSTR + (lane&31)*4;
  float a0=0.f, a1=0.f, a2=0.f, a3=0.f;
  for(unsigned j=s; j<e; ++j){
    const float w = svals[j];
    const ushort4 u = *(const ushort4*)(src + (size_t)scols[j]*SROW + off);
    a0 = fmaf(w, bs2f(u.x), a0);
    a1 = fmaf(w, bs2f(u.y), a1);
    a2 = fmaf(w, bs2f(u.z), a2);
    a3 = fmaf(w, bs2f(u.w), a3);
  }
  ushort4 o;
  o.x = (unsigned short)f2bs(a0); o.y = (unsigned short)f2bs(a1);
  o.z = (unsigned short)f2bs(a2); o.w = (unsigned short)f2bs(a3);
  *(ushort4*)(dst + (size_t)v*256 + lane*4) = o;
}

// ---------------- combined weights: wcb[q][k3], k3 = part*64 + p ----------------
// part0: W0-W2, part1: W1, part2: 2*W2, where Wk[p][q] = wf[(3p+k)*64+q].

__global__ void k_prepw(const float* __restrict__ wf, short* __restrict__ wcb){
  int idx = blockIdx.x*256 + threadIdx.x;      // 12288 total
  int q = idx/192, rem = idx%192, part = rem>>6, p = rem&63;
  float w;
  if(part==0)      w = wf[(3*p+0)*64+q] - wf[(3*p+2)*64+q];
  else if(part==1) w = wf[(3*p+1)*64+q];
  else             w = 2.0f*wf[(3*p+2)*64+q];
  wcb[idx] = f2bs(w);
}

// ---------------- MFMA GEMM epilogue ----------------
// out[b,v,q] = bias[q] + sum_k3 A[v-row,k3] * Wc[k3,q]
// A parts: [0,64): x0 (bf16, from x0c in d_out); [64,128): x1; [128,192): y.
// mfma_f32_16x16x32_bf16: A row=l&15, k=8*(l>>4)+i; C/D col=l&15, row=4*(l>>4)+reg.

#define WTP 200   // LDS pitch in bf16 elems: bank stride 4 -> conflict-free

__global__ __launch_bounds__(256) void k_gemm_mfma(const short* __restrict__ x0,
                      const short* __restrict__ x1, const short* __restrict__ y,
                      const short* __restrict__ wcb, const float* __restrict__ bias,
                      float* __restrict__ out){
  __shared__ short WT[64*WTP];    // 25600 B, [q][k3] padded
  const int t = threadIdx.x;
  for(int idx=t; idx<1536; idx+=256){
    const int row = idx/24, ch = idx%24;
    *(uint4*)&WT[row*WTP + ch*8] = ((const uint4*)wcb)[row*24 + ch];
  }
  const int w = t>>6;          // wave id = batch b
  const int l = t&63, r = l&15, g = l>>4;
  const size_t v0 = (size_t)blockIdx.x*64;
  f32x4 acc[4][4] = {};
  __syncthreads();

#pragma unroll
  for(int c=0; c<6; ++c){
    const int part = c>>1, ko = (c&1)*32;
    bf16x8 a[4];
    if(part==0){
      const short* sp = x0 + ((size_t)(w>>1)*Vn + v0 + r)*128 + (w&1)*64 + ko + 8*g;
#pragma unroll
      for(int m=0;m<4;++m) a[m] = *(const bf16x8*)(sp + (size_t)m*16*128);
    } else {
      const short* sp = (part==1 ? x1 : y) + ((v0 + r)*256 + w*64 + ko + 8*g);
#pragma unroll
      for(int m=0;m<4;++m) a[m] = *(const bf16x8*)(sp + (size_t)m*16*256);
    }
    const int kw = part*64 + ko + 8*g;
#pragma unroll
    for(int n=0;n<4;++n){
      const bf16x8 bfr = *(const bf16x8*)&WT[(n*16+r)*WTP + kw];
#pragma unroll
      for(int m=0;m<4;++m)
        acc[m][n] = __builtin_amdgcn_mfma_f32_16x16x32_bf16(a[m], bfr, acc[m][n], 0, 0, 0);
    }
  }

  __syncthreads();   // all x0c reads (in d_out) done before overwriting with out

  float* ob = out + (size_t)w*Vn*64 + v0*64;
#pragma unroll
  for(int n=0;n<4;++n){
    const float bq = bias[n*16+r];
#pragma unroll
    for(int m=0;m<4;++m){
#pragma unroll
      for(int reg=0;reg<4;++reg){
        const int row = m*16 + g*4 + reg;
        ob[(size_t)row*64 + n*16 + r] = acc[m][n][reg] + bq;
      }
    }
  }
}

// ---------------- launch ----------------

extern "C" void kernel_launch(void* const* d_in, const int* in_sizes, int n_in,
                              void* d_out, int out_size, void* d_ws, size_t ws_size,
                              hipStream_t stream){
  const float* lap_vals = (const float*)d_in[0];
  const float* x        = (const float*)d_in[1];
  const float* weight   = (const float*)d_in[2];
  const float* bias     = (const float*)d_in[3];
  const int*   lap_rows = (const int*)d_in[4];
  const int*   lap_cols = (const int*)d_in[5];
  float* out = (float*)d_out;
  short* x0c = (short*)d_out;   // bf16 x0 staged inside the output buffer

  char* w = (char*)d_ws;
  short* x1b = (short*)w;          w += (size_t)Vn*256*sizeof(short);
  short* yb  = (short*)w;          w += (size_t)Vn*256*sizeof(short);
  float* svals = (float*)w;        w += (size_t)NNZn*4;
  int*   scols = (int*)w;          w += (size_t)NNZn*4;
  unsigned* counts = (unsigned*)w; w += (size_t)Vn*4;
  unsigned* cursor = (unsigned*)w; w += (size_t)Vn*4;
  unsigned* rstart = (unsigned*)w; w += (size_t)Vn*4;
  unsigned* rend   = (unsigned*)w; w += (size_t)Vn*4;
  unsigned* bsums  = (unsigned*)w; w += 1024;
  short* wcb = (short*)w;          w += 12288*sizeof(short);

  k_zero<<<Vn/256, 256, 0, stream>>>(counts, Vn);
  k_hist<<<NNZn/256, 256, 0, stream>>>(lap_rows, counts);
  k_scan_block<<<192, 1024, 0, stream>>>(counts, rend, bsums);
  k_scan_top<<<1, 64, 0, stream>>>(bsums);
  k_scan_add<<<Vn/256, 256, 0, stream>>>(counts, rend, bsums, rstart, cursor);
  k_scatter<<<NNZn/256, 256, 0, stream>>>(lap_vals, lap_rows, lap_cols, cursor, svals, scols);
  k_prepw<<<48, 256, 0, stream>>>(weight, wcb);
  k_cvt<<<Vn*64/256, 256, 0, stream>>>(x, x0c);

  // x1 = L @ x0   (gather from x0c: piece-split rows, 2 x 256B segments)
  k_spmm<128, (size_t)Vn*128><<<Vn/4, 256, 0, stream>>>(x0c, svals, scols, rstart, rend, x1b);
  // y = L @ x1    (gather from x1b: flat rows, contiguous 512B)
  k_spmm<256, 128><<<Vn/4, 256, 0, stream>>>(x1b, svals, scols, rstart, rend, yb);

  k_gemm_mfma<<<Vn/64, 256, 0, stream>>>(x0c, x1b, yb, wcb, bias, out);
}

// Round 4
// 653.616 us; speedup vs baseline: 2.5907x; 1.1944x over previous
//
#include <hip/hip_runtime.h>
#include <hip/hip_bf16.h>

#define Vn   196608
#define NNZn 1769472
#define Bn   4
#define Pn   64
#define Qn   64
#define VPn  (Vn*Pn)

typedef __hip_bfloat16 bf16;
typedef __attribute__((ext_vector_type(8))) short bf16x8;
typedef __attribute__((ext_vector_type(4))) float f32x4;

__device__ inline short f2bs(float f){
  __hip_bfloat16 h = __float2bfloat16(f);
  return *(short*)&h;
}
__device__ inline float bs2f(unsigned short s){
  return __uint_as_float(((unsigned)s)<<16);
}

// ---------------- CSR build (counting sort) ----------------

__global__ void k_zero(unsigned* __restrict__ p, int n){
  int i = blockIdx.x*blockDim.x + threadIdx.x;
  if(i<n) p[i]=0u;
}

__global__ void k_hist(const int* __restrict__ rows, unsigned* __restrict__ counts){
  int i = blockIdx.x*blockDim.x + threadIdx.x;   // grid covers NNZ exactly
  atomicAdd(&counts[rows[i]], 1u);
}

__global__ __launch_bounds__(1024) void k_scan_block(const unsigned* __restrict__ counts,
                                                     unsigned* __restrict__ incl,
                                                     unsigned* __restrict__ bsums){
  __shared__ unsigned s[1024];
  const int tid = threadIdx.x;
  const int gid = blockIdx.x*1024 + tid;
  s[tid] = counts[gid];
  __syncthreads();
  for(int off=1; off<1024; off<<=1){
    unsigned v = (tid>=off) ? s[tid-off] : 0u;
    __syncthreads();
    s[tid] += v;
    __syncthreads();
  }
  incl[gid] = s[tid];
  if(tid==1023) bsums[blockIdx.x] = s[1023];
}

__global__ void k_scan_top(unsigned* __restrict__ bs){
  if(blockIdx.x==0 && threadIdx.x==0){
    unsigned acc=0u;
    for(int i=0;i<192;i++){ unsigned t=bs[i]; bs[i]=acc; acc+=t; }
  }
}

__global__ void k_scan_add(const unsigned* __restrict__ counts, unsigned* __restrict__ incl,
                           const unsigned* __restrict__ boffs,
                           unsigned* __restrict__ rstart, unsigned* __restrict__ cursor){
  int i = blockIdx.x*blockDim.x + threadIdx.x;   // grid covers V exactly
  unsigned e = incl[i] + boffs[i>>10];
  incl[i] = e;
  unsigned st = e - counts[i];
  rstart[i] = st;
  cursor[i] = st;
}

__global__ void k_scatter(const float* __restrict__ vals, const int* __restrict__ rows,
                          const int* __restrict__ cols, unsigned* __restrict__ cursor,
                          float* __restrict__ svals, int* __restrict__ scols){
  int i = blockIdx.x*blockDim.x + threadIdx.x;   // grid covers NNZ exactly
  int r = rows[i];
  unsigned pos = atomicAdd(&cursor[r], 1u);
  svals[pos] = vals[i];
  scols[pos] = cols[i];
}

// ---------------- x -> bf16 x0c, stored INSIDE d_out ----------------
// x0c piece h (h=b>>1) of row v lives at shorts offset (h*Vn + v)*128, i.e.
// exactly the out-fp32 bytes of batch h, row v -- each gemm block's x0 reads
// are inside its own out-write region (race-free with an intra-block barrier).

__global__ void k_cvt(const float* __restrict__ x, short* __restrict__ x0c){
  const int i = blockIdx.x*256 + threadIdx.x;    // V*256/4 threads
  const int o = i*4;
  const int v = o>>8, bp = o&255;
  const int h = bp>>7, w7 = bp&127;
  const int b = (h<<1) + (w7>>6), p = w7&63;
  const float4 f = *(const float4*)(x + (size_t)b*VPn + (size_t)v*64 + p);
  ushort4 u;
  u.x = (unsigned short)f2bs(f.x); u.y = (unsigned short)f2bs(f.y);
  u.z = (unsigned short)f2bs(f.z); u.w = (unsigned short)f2bs(f.w);
  *(ushort4*)(x0c + ((size_t)h*Vn + v)*128 + w7) = u;
}

// ---------------- SpMM: one wave per row, depth-4 software pipeline ----------
// dst: flat [V][256] bf16. Source addressing: elem e of row c at
// src + c*SROW + (e>>7)*PSTR + (e&127)   (SROW=256,PSTR=128 -> flat).
// All stage slots use NAMED registers (static indexing only, rule #20).
// Dead slots (row length % 4) clamp the column to one already in flight and
// use weight 0 -> L1/MSHR hit, no extra L2 traffic, fma adds 0.

template<int SROW, size_t PSTR>
__global__ __launch_bounds__(256) void k_spmm(const short* __restrict__ src,
                          const float* __restrict__ svals, const int* __restrict__ scols,
                          const unsigned* __restrict__ rstart, const unsigned* __restrict__ rend,
                          short* __restrict__ dst){
  const int lane = threadIdx.x & 63;
  const int v = (blockIdx.x<<2) + (threadIdx.x>>6);
  const unsigned s = rstart[v], e = rend[v];
  const size_t off = (size_t)(lane>>5)*PSTR + (size_t)((lane&31)*4);
  float a0=0.f, a1=0.f, a2=0.f, a3=0.f;
  const int n = (int)e - (int)s;
  if(n > 0){
    ushort4 u0,u1,u2,u3;
    float w0,w1,w2,w3;
    const int cF = scols[s];
    // prologue: stage slots s..s+3
    {
      const int c1 = (n>1)? scols[s+1] : cF;
      const int c2 = (n>2)? scols[s+2] : cF;
      const int c3 = (n>3)? scols[s+3] : cF;
      w0 = svals[s];
      w1 = (n>1)? svals[s+1] : 0.f;
      w2 = (n>2)? svals[s+2] : 0.f;
      w3 = (n>3)? svals[s+3] : 0.f;
      u0 = *(const ushort4*)(src + (size_t)cF*SROW + off);
      u1 = *(const ushort4*)(src + (size_t)c1*SROW + off);
      u2 = *(const ushort4*)(src + (size_t)c2*SROW + off);
      u3 = *(const ushort4*)(src + (size_t)c3*SROW + off);
    }
    int rem = n - 4;
    unsigned j = s + 4;
    while(rem > 0){
      // rotate staged -> consume regs
      const ushort4 v0=u0, v1=u1, v2=u2, v3=u3;
      const float  y0=w0, y1=w1, y2=w2, y3=w3;
      // issue next 4 (wave-uniform predicates; dead slots clamp to c0)
      const int c0 = scols[j];
      const int c1 = (rem>1)? scols[j+1] : c0;
      const int c2 = (rem>2)? scols[j+2] : c0;
      const int c3 = (rem>3)? scols[j+3] : c0;
      w0 = svals[j];
      w1 = (rem>1)? svals[j+1] : 0.f;
      w2 = (rem>2)? svals[j+2] : 0.f;
      w3 = (rem>3)? svals[j+3] : 0.f;
      u0 = *(const ushort4*)(src + (size_t)c0*SROW + off);
      u1 = *(const ushort4*)(src + (size_t)c1*SROW + off);
      u2 = *(const ushort4*)(src + (size_t)c2*SROW + off);
      u3 = *(const ushort4*)(src + (size_t)c3*SROW + off);
      // consume previous batch
      a0 = fmaf(y0, bs2f(v0.x), a0); a1 = fmaf(y0, bs2f(v0.y), a1);
      a2 = fmaf(y0, bs2f(v0.z), a2); a3 = fmaf(y0, bs2f(v0.w), a3);
      a0 = fmaf(y1, bs2f(v1.x), a0); a1 = fmaf(y1, bs2f(v1.y), a1);
      a2 = fmaf(y1, bs2f(v1.z), a2); a3 = fmaf(y1, bs2f(v1.w), a3);
      a0 = fmaf(y2, bs2f(v2.x), a0); a1 = fmaf(y2, bs2f(v2.y), a1);
      a2 = fmaf(y2, bs2f(v2.z), a2); a3 = fmaf(y2, bs2f(v2.w), a3);
      a0 = fmaf(y3, bs2f(v3.x), a0); a1 = fmaf(y3, bs2f(v3.y), a1);
      a2 = fmaf(y3, bs2f(v3.z), a2); a3 = fmaf(y3, bs2f(v3.w), a3);
      rem -= 4; j += 4;
    }
    // epilogue: consume last staged batch
    a0 = fmaf(w0, bs2f(u0.x), a0); a1 = fmaf(w0, bs2f(u0.y), a1);
    a2 = fmaf(w0, bs2f(u0.z), a2); a3 = fmaf(w0, bs2f(u0.w), a3);
    a0 = fmaf(w1, bs2f(u1.x), a0); a1 = fmaf(w1, bs2f(u1.y), a1);
    a2 = fmaf(w1, bs2f(u1.z), a2); a3 = fmaf(w1, bs2f(u1.w), a3);
    a0 = fmaf(w2, bs2f(u2.x), a0); a1 = fmaf(w2, bs2f(u2.y), a1);
    a2 = fmaf(w2, bs2f(u2.z), a2); a3 = fmaf(w2, bs2f(u2.w), a3);
    a0 = fmaf(w3, bs2f(u3.x), a0); a1 = fmaf(w3, bs2f(u3.y), a1);
    a2 = fmaf(w3, bs2f(u3.z), a2); a3 = fmaf(w3, bs2f(u3.w), a3);
  }
  ushort4 o;
  o.x = (unsigned short)f2bs(a0); o.y = (unsigned short)f2bs(a1);
  o.z = (unsigned short)f2bs(a2); o.w = (unsigned short)f2bs(a3);
  *(ushort4*)(dst + (size_t)v*256 + lane*4) = o;
}

// ---------------- combined weights: wcb[q][k3], k3 = part*64 + p ----------------
// part0: W0-W2, part1: W1, part2: 2*W2, where Wk[p][q] = wf[(3p+k)*64+q].

__global__ void k_prepw(const float* __restrict__ wf, short* __restrict__ wcb){
  int idx = blockIdx.x*256 + threadIdx.x;      // 12288 total
  int q = idx/192, rem = idx%192, part = rem>>6, p = rem&63;
  float w;
  if(part==0)      w = wf[(3*p+0)*64+q] - wf[(3*p+2)*64+q];
  else if(part==1) w = wf[(3*p+1)*64+q];
  else             w = 2.0f*wf[(3*p+2)*64+q];
  wcb[idx] = f2bs(w);
}

// ---------------- MFMA GEMM epilogue ----------------
// out[b,v,q] = bias[q] + sum_k3 A[v-row,k3] * Wc[k3,q]
// A parts: [0,64): x0 (bf16, from x0c in d_out); [64,128): x1; [128,192): y.
// mfma_f32_16x16x32_bf16: A row=l&15, k=8*(l>>4)+i; C/D col=l&15, row=4*(l>>4)+reg.

#define WTP 200   // LDS pitch in bf16 elems: bank stride 4 -> conflict-free

__global__ __launch_bounds__(256) void k_gemm_mfma(const short* __restrict__ x0,
                      const short* __restrict__ x1, const short* __restrict__ y,
                      const short* __restrict__ wcb, const float* __restrict__ bias,
                      float* __restrict__ out){
  __shared__ short WT[64*WTP];    // 25600 B, [q][k3] padded
  const int t = threadIdx.x;
  for(int idx=t; idx<1536; idx+=256){
    const int row = idx/24, ch = idx%24;
    *(uint4*)&WT[row*WTP + ch*8] = ((const uint4*)wcb)[row*24 + ch];
  }
  const int w = t>>6;          // wave id = batch b
  const int l = t&63, r = l&15, g = l>>4;
  const size_t v0 = (size_t)blockIdx.x*64;
  f32x4 acc[4][4] = {};
  __syncthreads();

#pragma unroll
  for(int c=0; c<6; ++c){
    const int part = c>>1, ko = (c&1)*32;
    bf16x8 a[4];
    if(part==0){
      const short* sp = x0 + ((size_t)(w>>1)*Vn + v0 + r)*128 + (w&1)*64 + ko + 8*g;
#pragma unroll
      for(int m=0;m<4;++m) a[m] = *(const bf16x8*)(sp + (size_t)m*16*128);
    } else {
      const short* sp = (part==1 ? x1 : y) + ((v0 + r)*256 + w*64 + ko + 8*g);
#pragma unroll
      for(int m=0;m<4;++m) a[m] = *(const bf16x8*)(sp + (size_t)m*16*256);
    }
    const int kw = part*64 + ko + 8*g;
#pragma unroll
    for(int n=0;n<4;++n){
      const bf16x8 bfr = *(const bf16x8*)&WT[(n*16+r)*WTP + kw];
#pragma unroll
      for(int m=0;m<4;++m)
        acc[m][n] = __builtin_amdgcn_mfma_f32_16x16x32_bf16(a[m], bfr, acc[m][n], 0, 0, 0);
    }
  }

  __syncthreads();   // all x0c reads (in d_out) done before overwriting with out

  float* ob = out + (size_t)w*Vn*64 + v0*64;
#pragma unroll
  for(int n=0;n<4;++n){
    const float bq = bias[n*16+r];
#pragma unroll
    for(int m=0;m<4;++m){
#pragma unroll
      for(int reg=0;reg<4;++reg){
        const int row = m*16 + g*4 + reg;
        ob[(size_t)row*64 + n*16 + r] = acc[m][n][reg] + bq;
      }
    }
  }
}

// ---------------- launch ----------------

extern "C" void kernel_launch(void* const* d_in, const int* in_sizes, int n_in,
                              void* d_out, int out_size, void* d_ws, size_t ws_size,
                              hipStream_t stream){
  const float* lap_vals = (const float*)d_in[0];
  const float* x        = (const float*)d_in[1];
  const float* weight   = (const float*)d_in[2];
  const float* bias     = (const float*)d_in[3];
  const int*   lap_rows = (const int*)d_in[4];
  const int*   lap_cols = (const int*)d_in[5];
  float* out = (float*)d_out;
  short* x0c = (short*)d_out;   // bf16 x0 staged inside the output buffer

  char* w = (char*)d_ws;
  short* x1b = (short*)w;          w += (size_t)Vn*256*sizeof(short);
  short* yb  = (short*)w;          w += (size_t)Vn*256*sizeof(short);
  float* svals = (float*)w;        w += (size_t)NNZn*4;
  int*   scols = (int*)w;          w += (size_t)NNZn*4;
  unsigned* counts = (unsigned*)w; w += (size_t)Vn*4;
  unsigned* cursor = (unsigned*)w; w += (size_t)Vn*4;
  unsigned* rstart = (unsigned*)w; w += (size_t)Vn*4;
  unsigned* rend   = (unsigned*)w; w += (size_t)Vn*4;
  unsigned* bsums  = (unsigned*)w; w += 1024;
  short* wcb = (short*)w;          w += 12288*sizeof(short);

  k_zero<<<Vn/256, 256, 0, stream>>>(counts, Vn);
  k_hist<<<NNZn/256, 256, 0, stream>>>(lap_rows, counts);
  k_scan_block<<<192, 1024, 0, stream>>>(counts, rend, bsums);
  k_scan_top<<<1, 64, 0, stream>>>(bsums);
  k_scan_add<<<Vn/256, 256, 0, stream>>>(counts, rend, bsums, rstart, cursor);
  k_scatter<<<NNZn/256, 256, 0, stream>>>(lap_vals, lap_rows, lap_cols, cursor, svals, scols);
  k_prepw<<<48, 256, 0, stream>>>(weight, wcb);
  k_cvt<<<Vn*64/256, 256, 0, stream>>>(x, x0c);

  // x1 = L @ x0   (gather from x0c: piece-split rows, 2 x 256B segments)
  k_spmm<128, (size_t)Vn*128><<<Vn/4, 256, 0, stream>>>(x0c, svals, scols, rstart, rend, x1b);
  // y = L @ x1    (gather from x1b: flat rows, contiguous 512B)
  k_spmm<256, 128><<<Vn/4, 256, 0, stream>>>(x1b, svals, scols, rstart, rend, yb);

  k_gemm_mfma<<<Vn/64, 256, 0, stream>>>(x0c, x1b, yb, wcb, bias, out);
}